// Round 1
// 481.203 us; speedup vs baseline: 1.0446x; 1.0446x over previous
//
#include <hip/hip_runtime.h>
#include <hip/hip_fp16.h>

// Problem: B=64, L=512, D=512, A=512
//   F_p = tanh(P @ W), F_h = tanh(H @ W)        [f16 in ws; 2-term split MFMA:
//                                                Ah*(Bh+Bl), A-lo dropped --
//                                                err ~ f16-storage floor of F]
//   S = F_p @ F_h^T ; attn = softmax_rows(S)    [fused, attn f16 in ws]
//   betas  = attn   @ H  -> d_out[0 .. 16M)
//   alphas = attn^T @ P  -> d_out[16M .. 32M)
//
// ws layout (f16 elems), total 100.66 MB:
//   [0, 33554432)          F_p|F_h   -- dead after score; reused for PT|HT
//   [33554432, 50331648)   WT_H|WT_L (1MB, dead after proj) then attn (score output)

#define NB 64
#define NL 512
#define ND 512
#define BATCH_ELEMS (512 * 512)            // 262144
#define TOT_ELEMS   ((size_t)NB * NL * ND) // 16777216

typedef _Float16 h8 __attribute__((ext_vector_type(8)));
typedef float f4 __attribute__((ext_vector_type(4)));

// LDS tile layout: [row][32 k] f16, 16B chunks XOR-swizzled by ((row>>1)^(row>>4))&3.
__device__ __forceinline__ int swz(int row, int chunk) {
    return (row << 5) + ((chunk ^ (((row >> 1) ^ (row >> 4)) & 3)) << 3);
}

__device__ __forceinline__ float fast_tanh(float x) {
    float e = __expf(2.0f * x);            // inf-safe: x>>0 -> 1, x<<0 -> -1
    return 1.0f - 2.0f / (e + 1.0f);
}

// ------------- Prep: out[c][r] = f16(src[r][c]) (+ lo residual) --------------
// Used only for W (1 block-layer); H/P use the merged kernel below.
template <bool WITH_LO>
__global__ __launch_bounds__(256) void transpose_f16_kernel(
    const float* __restrict__ src, _Float16* __restrict__ dstH,
    _Float16* __restrict__ dstL)
{
    __shared__ float tile[64 * 68];
    const size_t base = (size_t)blockIdx.z * BATCH_ELEMS;
    const int r0 = blockIdx.y * 64, c0 = blockIdx.x * 64;
    const int t = threadIdx.x;
    {
        int r = t >> 2, cq = (t & 3) * 16;
        const float* sp = src + base + (size_t)(r0 + r) * 512 + c0 + cq;
        *(float4*)&tile[r * 68 + cq]      = ((const float4*)sp)[0];
        *(float4*)&tile[r * 68 + cq + 4]  = ((const float4*)sp)[1];
        *(float4*)&tile[r * 68 + cq + 8]  = ((const float4*)sp)[2];
        *(float4*)&tile[r * 68 + cq + 12] = ((const float4*)sp)[3];
    }
    __syncthreads();
    {
        int c = t >> 2, rq = (t & 3) * 16;
        _Float16 hv[16], lv[16];
#pragma unroll
        for (int j = 0; j < 16; ++j) {
            float v = tile[(rq + j) * 68 + c];
            hv[j] = (_Float16)v;
            if (WITH_LO) lv[j] = (_Float16)(v - (float)hv[j]);
        }
        _Float16* dp = dstH + base + (size_t)(c0 + c) * 512 + r0 + rq;
        *(h8*)dp = *(h8*)&hv[0];
        *(h8*)(dp + 8) = *(h8*)&hv[8];
        if (WITH_LO) {
            _Float16* dl = dstL + base + (size_t)(c0 + c) * 512 + r0 + rq;
            *(h8*)dl = *(h8*)&lv[0];
            *(h8*)(dl + 8) = *(h8*)&lv[8];
        }
    }
}

// ------------- Prep: HT and PT in ONE launch (z<64: H, z>=64: P) -------------
__global__ __launch_bounds__(256) void transpose_hp_kernel(
    const float* __restrict__ H, const float* __restrict__ P,
    _Float16* __restrict__ HT, _Float16* __restrict__ PT)
{
    __shared__ float tile[64 * 68];
    const int z = blockIdx.z;
    const float* src = (z < NB) ? H : P;
    _Float16* dst = (z < NB) ? HT : PT;
    const size_t base = (size_t)(z < NB ? z : z - NB) * BATCH_ELEMS;
    const int r0 = blockIdx.y * 64, c0 = blockIdx.x * 64;
    const int t = threadIdx.x;
    {
        int r = t >> 2, cq = (t & 3) * 16;
        const float* sp = src + base + (size_t)(r0 + r) * 512 + c0 + cq;
        *(float4*)&tile[r * 68 + cq]      = ((const float4*)sp)[0];
        *(float4*)&tile[r * 68 + cq + 4]  = ((const float4*)sp)[1];
        *(float4*)&tile[r * 68 + cq + 8]  = ((const float4*)sp)[2];
        *(float4*)&tile[r * 68 + cq + 12] = ((const float4*)sp)[3];
    }
    __syncthreads();
    {
        int c = t >> 2, rq = (t & 3) * 16;
        _Float16 hv[16];
#pragma unroll
        for (int j = 0; j < 16; ++j) hv[j] = (_Float16)tile[(rq + j) * 68 + c];
        _Float16* dp = dst + base + (size_t)(c0 + c) * 512 + r0 + rq;
        *(h8*)dp = *(h8*)&hv[0];
        *(h8*)(dp + 8) = *(h8*)&hv[8];
    }
}

// ---------------- Kernel 1: F = tanh(X @ W), 2-term split f16 MFMA -----------
// A = f16(X) (hi only), B = WT hi/lo. Dropped Al*B term has sigma~0.003 on the
// tanh argument -- same order as the f16 storage error of F itself.
__global__ __launch_bounds__(256) void proj_tanh_kernel(
    const float* __restrict__ P, const float* __restrict__ H,
    const _Float16* __restrict__ WTH, const _Float16* __restrict__ WTL,
    _Float16* __restrict__ Fout)
{
    __shared__ __align__(16) _Float16 AsH[128 * 32];
    __shared__ __align__(16) _Float16 BsH[128 * 32], BsL[128 * 32];

    const int z = blockIdx.z;
    const float* X = z ? H : P;
    _Float16* F = Fout + (size_t)z * TOT_ELEMS;
    const int r0 = blockIdx.x * 128;   // row tile fastest -> col-blocks of same
    const int n0 = blockIdx.y * 128;   // rows land on same XCD (ids differ by 256)

    const int t = threadIdx.x;
    const int lane = t & 63, w = t >> 6;
    const int q = lane >> 4, c = lane & 15;
    const int wm = w >> 1, wn = w & 1;

    f4 acc[4][4] = {};

    const int ar = t >> 1, akq = (t & 1) << 4;   // A stage: row, k-offset 0/16
    const int br = t >> 1, bcp = (t & 1) << 1;   // B stage: n-row, chunk pair

    for (int k0 = 0; k0 < 512; k0 += 32) {
        // stage A tile (128x32 fp32 -> f16 hi only)
        {
            const float* ap = X + (size_t)(r0 + ar) * 512 + k0 + akq;
            float av[16];
            *(float4*)&av[0]  = ((const float4*)ap)[0];
            *(float4*)&av[4]  = ((const float4*)ap)[1];
            *(float4*)&av[8]  = ((const float4*)ap)[2];
            *(float4*)&av[12] = ((const float4*)ap)[3];
            const int cbase = akq >> 3;
#pragma unroll
            for (int jj = 0; jj < 2; ++jj) {
                h8 hv;
#pragma unroll
                for (int i = 0; i < 8; ++i) hv[i] = (_Float16)av[jj * 8 + i];
                *(h8*)&AsH[swz(ar, cbase + jj)] = hv;
            }
        }
        // stage B tile: pure vector copy from precomputed WT hi/lo
        {
            const _Float16* bh = WTH + (size_t)(n0 + br) * 512 + k0 + bcp * 8;
            const _Float16* bl = WTL + (size_t)(n0 + br) * 512 + k0 + bcp * 8;
            *(h8*)&BsH[swz(br, bcp)]     = ((const h8*)bh)[0];
            *(h8*)&BsH[swz(br, bcp + 1)] = ((const h8*)bh)[1];
            *(h8*)&BsL[swz(br, bcp)]     = ((const h8*)bl)[0];
            *(h8*)&BsL[swz(br, bcp + 1)] = ((const h8*)bl)[1];
        }
        __syncthreads();

        h8 aH[4], bH[4], bL[4];
#pragma unroll
        for (int mi = 0; mi < 4; ++mi) {
            int row = wm * 64 + mi * 16 + c;
            aH[mi] = *(const h8*)&AsH[swz(row, q)];
        }
#pragma unroll
        for (int ni = 0; ni < 4; ++ni) {
            int col = wn * 64 + ni * 16 + c;
            bH[ni] = *(const h8*)&BsH[swz(col, q)];
            bL[ni] = *(const h8*)&BsL[swz(col, q)];
        }
#pragma unroll
        for (int mi = 0; mi < 4; ++mi)
#pragma unroll
            for (int ni = 0; ni < 4; ++ni) {
                acc[mi][ni] = __builtin_amdgcn_mfma_f32_16x16x32_f16(aH[mi], bH[ni], acc[mi][ni], 0, 0, 0);
                acc[mi][ni] = __builtin_amdgcn_mfma_f32_16x16x32_f16(aH[mi], bL[ni], acc[mi][ni], 0, 0, 0);
            }
        __syncthreads();
    }

#pragma unroll
    for (int mi = 0; mi < 4; ++mi)
#pragma unroll
        for (int ni = 0; ni < 4; ++ni) {
            int col = n0 + wn * 64 + ni * 16 + c;
            int rowb = r0 + wm * 64 + mi * 16 + q * 4;
#pragma unroll
            for (int r = 0; r < 4; ++r)
                F[(size_t)(rowb + r) * 512 + col] = (_Float16)fast_tanh(acc[mi][ni][r]);
        }
}

// ---------------- Kernel 2: S = F_p @ F_h^T, row softmax -> attn f16 ---------
__global__ __launch_bounds__(256) void score_softmax_kernel(
    const _Float16* __restrict__ Fbase, _Float16* __restrict__ attn)
{
    __shared__ __align__(16) _Float16 As[64 * 32];
    __shared__ __align__(16) _Float16 Bs[512 * 32];
    __shared__ float redM[4 * 64], redS[4 * 64];

    const _Float16* Fp = Fbase;
    const _Float16* Fh = Fbase + TOT_ELEMS;
    const int b = blockIdx.y;
    const int p0 = blockIdx.x * 64;
    const size_t fb = (size_t)b * BATCH_ELEMS;

    const int t = threadIdx.x, lane = t & 63, w = t >> 6;
    const int q = lane >> 4, c = lane & 15;

    f4 acc[4][8] = {};

    for (int k0 = 0; k0 < 512; k0 += 32) {
        {   // A: F_p rows [p0, p0+64) x 32k  (direct, f16)
            int row = t >> 2, ch = t & 3;
            *(h8*)&As[swz(row, ch)] =
                *(const h8*)(Fp + fb + (size_t)(p0 + row) * 512 + k0 + ch * 8);
        }
        {   // B: F_h rows [0,512) x 32k -> Bs[h][k] (direct: B[k][n]=F_h[n][k])
#pragma unroll
            for (int rr = 0; rr < 2; ++rr) {
                int row = t * 2 + rr;
#pragma unroll
                for (int ch = 0; ch < 4; ++ch)
                    *(h8*)&Bs[swz(row, ch)] =
                        *(const h8*)(Fh + fb + (size_t)row * 512 + k0 + ch * 8);
            }
        }
        __syncthreads();

        h8 a[4], bb[8];
#pragma unroll
        for (int mt = 0; mt < 4; ++mt) a[mt] = *(const h8*)&As[swz(mt * 16 + c, q)];
#pragma unroll
        for (int nt = 0; nt < 8; ++nt) bb[nt] = *(const h8*)&Bs[swz(w * 128 + nt * 16 + c, q)];
#pragma unroll
        for (int mt = 0; mt < 4; ++mt)
#pragma unroll
            for (int nt = 0; nt < 8; ++nt)
                acc[mt][nt] = __builtin_amdgcn_mfma_f32_16x16x32_f16(a[mt], bb[nt], acc[mt][nt], 0, 0, 0);
        __syncthreads();
    }

    // ---- softmax over the 512 cols; rows owned: mt*16 + q*4 + r ----
    float rmax[4][4];
#pragma unroll
    for (int mt = 0; mt < 4; ++mt)
#pragma unroll
        for (int r = 0; r < 4; ++r) {
            float m = acc[mt][0][r];
#pragma unroll
            for (int nt = 1; nt < 8; ++nt) m = fmaxf(m, acc[mt][nt][r]);
            rmax[mt][r] = m;
        }
#pragma unroll
    for (int s = 1; s < 16; s <<= 1)
#pragma unroll
        for (int mt = 0; mt < 4; ++mt)
#pragma unroll
            for (int r = 0; r < 4; ++r)
                rmax[mt][r] = fmaxf(rmax[mt][r], __shfl_xor(rmax[mt][r], s, 64));
    if (c == 0)
#pragma unroll
        for (int mt = 0; mt < 4; ++mt)
#pragma unroll
            for (int r = 0; r < 4; ++r)
                redM[w * 64 + mt * 16 + q * 4 + r] = rmax[mt][r];
    __syncthreads();

    float gmax[4][4];
#pragma unroll
    for (int mt = 0; mt < 4; ++mt)
#pragma unroll
        for (int r = 0; r < 4; ++r) {
            int row = mt * 16 + q * 4 + r;
            float m = redM[row];
#pragma unroll
            for (int w4 = 1; w4 < 4; ++w4) m = fmaxf(m, redM[w4 * 64 + row]);
            gmax[mt][r] = m;
        }

    float rsum[4][4] = {};
#pragma unroll
    for (int mt = 0; mt < 4; ++mt)
#pragma unroll
        for (int nt = 0; nt < 8; ++nt)
#pragma unroll
            for (int r = 0; r < 4; ++r) {
                float e = __expf(acc[mt][nt][r] - gmax[mt][r]);
                acc[mt][nt][r] = e;
                rsum[mt][r] += e;
            }
#pragma unroll
    for (int s = 1; s < 16; s <<= 1)
#pragma unroll
        for (int mt = 0; mt < 4; ++mt)
#pragma unroll
            for (int r = 0; r < 4; ++r)
                rsum[mt][r] += __shfl_xor(rsum[mt][r], s, 64);
    if (c == 0)
#pragma unroll
        for (int mt = 0; mt < 4; ++mt)
#pragma unroll
            for (int r = 0; r < 4; ++r)
                redS[w * 64 + mt * 16 + q * 4 + r] = rsum[mt][r];
    __syncthreads();

    float inv[4][4];
#pragma unroll
    for (int mt = 0; mt < 4; ++mt)
#pragma unroll
        for (int r = 0; r < 4; ++r) {
            int row = mt * 16 + q * 4 + r;
            float s = redS[row] + redS[64 + row] + redS[128 + row] + redS[192 + row];
            inv[mt][r] = 1.0f / s;
        }

#pragma unroll
    for (int mt = 0; mt < 4; ++mt)
#pragma unroll
        for (int nt = 0; nt < 8; ++nt) {
            int col = w * 128 + nt * 16 + c;
#pragma unroll
            for (int r = 0; r < 4; ++r) {
                int row = p0 + mt * 16 + q * 4 + r;
                attn[fb + (size_t)row * 512 + col] = (_Float16)(acc[mt][nt][r] * inv[mt][r]);
            }
        }
}

// ------- Kernels 3+4 merged: C = A(^T) @ B; z<64: betas (attn@H via HT),
//         z>=64: alphas (attn^T@P via PT). Uniform scalar branch on staging. --
__global__ __launch_bounds__(256) void out_gemm_kernel(
    const _Float16* __restrict__ Amat, const _Float16* __restrict__ HT,
    const _Float16* __restrict__ PT, float* __restrict__ out)
{
    __shared__ __align__(16) _Float16 As[128 * 32];
    __shared__ __align__(16) _Float16 Bs[128 * 32];

    const int zz = blockIdx.z;
    const bool transA = zz >= NB;
    const int b = transA ? zz - NB : zz;
    const _Float16* BT = transA ? PT : HT;
    float* Cout = transA ? out + TOT_ELEMS : out;

    const int bn = blockIdx.x * 128, bm = blockIdx.y * 128;
    const size_t base = (size_t)b * BATCH_ELEMS;

    const int t = threadIdx.x, lane = t & 63, w = t >> 6;
    const int q = lane >> 4, c = lane & 15;
    const int wm = w >> 1, wn = w & 1;

    f4 acc[4][4] = {};

    for (int k0 = 0; k0 < 512; k0 += 32) {
        if (!transA) {  // As[m=p][k=h] <- attn[p][h] direct
            int row = t >> 1, cp = (t & 1) * 2;
            const _Float16* ap = Amat + base + (size_t)(bm + row) * 512 + k0 + cp * 8;
            *(h8*)&As[swz(row, cp)]     = ((const h8*)ap)[0];
            *(h8*)&As[swz(row, cp + 1)] = ((const h8*)ap)[1];
        } else {         // As[m=h][k=p] <- attn[p][h] transposed in LDS
            int kk = t >> 3, m0 = (t & 7) * 16;
            const _Float16* ap = Amat + base + (size_t)(k0 + kk) * 512 + bm + m0;
            h8 x0 = ((const h8*)ap)[0];
            h8 x1 = ((const h8*)ap)[1];
#pragma unroll
            for (int j = 0; j < 8; ++j) {
                As[swz(m0 + j, kk >> 3) + (kk & 7)]     = x0[j];
                As[swz(m0 + 8 + j, kk >> 3) + (kk & 7)] = x1[j];
            }
        }
        {   // Bs[n=d][k] <- BT[d][k] direct vector copy
            int row = t >> 1, cp = (t & 1) * 2;
            const _Float16* bp = BT + base + (size_t)(bn + row) * 512 + k0 + cp * 8;
            *(h8*)&Bs[swz(row, cp)]     = ((const h8*)bp)[0];
            *(h8*)&Bs[swz(row, cp + 1)] = ((const h8*)bp)[1];
        }
        __syncthreads();

        h8 a[4], bb[4];
#pragma unroll
        for (int mi = 0; mi < 4; ++mi) a[mi] = *(const h8*)&As[swz(wm * 64 + mi * 16 + c, q)];
#pragma unroll
        for (int ni = 0; ni < 4; ++ni) bb[ni] = *(const h8*)&Bs[swz(wn * 64 + ni * 16 + c, q)];
#pragma unroll
        for (int mi = 0; mi < 4; ++mi)
#pragma unroll
            for (int ni = 0; ni < 4; ++ni)
                acc[mi][ni] = __builtin_amdgcn_mfma_f32_16x16x32_f16(a[mi], bb[ni], acc[mi][ni], 0, 0, 0);
        __syncthreads();
    }

#pragma unroll
    for (int mi = 0; mi < 4; ++mi)
#pragma unroll
        for (int ni = 0; ni < 4; ++ni) {
            int col = bn + wn * 64 + ni * 16 + c;
            int rowb = bm + wm * 64 + mi * 16 + q * 4;
#pragma unroll
            for (int r = 0; r < 4; ++r)
                Cout[base + (size_t)(rowb + r) * 512 + col] = acc[mi][ni][r];
        }
}

extern "C" void kernel_launch(void* const* d_in, const int* in_sizes, int n_in,
                              void* d_out, int out_size, void* d_ws, size_t ws_size,
                              hipStream_t stream) {
    const float* P = (const float*)d_in[0];
    const float* H = (const float*)d_in[1];
    const float* W = (const float*)d_in[2];
    float* out = (float*)d_out;

    _Float16* ws16 = (_Float16*)d_ws;
    _Float16* F    = ws16;                       // F_p|F_h: 2*16777216 (dead after score)
    _Float16* PT   = ws16;                       // reuses F region after score
    _Float16* HT   = ws16 + TOT_ELEMS;
    _Float16* attn = ws16 + 2 * TOT_ELEMS;       // 16777216
    _Float16* WTH  = attn;                       // WT lives in attn region (dead
    _Float16* WTL  = attn + BATCH_ELEMS;         //  before score writes attn)

    transpose_f16_kernel<true><<<dim3(8, 8, 1), 256, 0, stream>>>(W, WTH, WTL);
    proj_tanh_kernel<<<dim3(256, 4, 2), 256, 0, stream>>>(P, H, WTH, WTL, F);
    score_softmax_kernel<<<dim3(8, NB), 256, 0, stream>>>(F, attn);
    transpose_hp_kernel<<<dim3(8, 8, 2 * NB), 256, 0, stream>>>(H, P, HT, PT);
    out_gemm_kernel<<<dim3(4, 4, 2 * NB), 256, 0, stream>>>(attn, HT, PT, out);
}

// Round 2
// 473.365 us; speedup vs baseline: 1.0619x; 1.0166x over previous
//
#include <hip/hip_runtime.h>
#include <hip/hip_fp16.h>

// Problem: B=64, L=512, D=512, A=512
//   F_p = tanh(P @ W), F_h = tanh(H @ W)        [f16 in ws; 2-term split MFMA:
//                                                Ah*(Bh+Bl), A-lo dropped]
//   S = F_p @ F_h^T ; attn = softmax_rows(S)    [fused, attn f16 in ws]
//   betas  = attn   @ H  -> d_out[0 .. 16M)
//   alphas = attn^T @ P  -> d_out[16M .. 32M)
//
// R2: all GEMM k-loops converted to single-barrier double-buffered pipeline:
//   barrier -> issue loads(k+1) -> ds_read frags(k) -> MFMA(k) -> ds_write(k+1)
// Global-load latency overlaps MFMA instead of sitting on the critical path.
//
// ws layout (f16 elems), total 100.66 MB:
//   [0, 33554432)          F_p|F_h   -- dead after score; reused for PT|HT
//   [33554432, 50331648)   WT_H|WT_L (1MB, dead after proj) then attn

#define NB 64
#define NL 512
#define ND 512
#define BATCH_ELEMS (512 * 512)            // 262144
#define TOT_ELEMS   ((size_t)NB * NL * ND) // 16777216

typedef _Float16 h8 __attribute__((ext_vector_type(8)));
typedef float f4 __attribute__((ext_vector_type(4)));

// LDS tile layout: [row][32 k] f16, 16B chunks XOR-swizzled by ((row>>1)^(row>>4))&3.
__device__ __forceinline__ int swz(int row, int chunk) {
    return (row << 5) + ((chunk ^ (((row >> 1) ^ (row >> 4)) & 3)) << 3);
}

__device__ __forceinline__ float fast_tanh(float x) {
    float e = __expf(2.0f * x);            // inf-safe: x>>0 -> 1, x<<0 -> -1
    return 1.0f - 2.0f / (e + 1.0f);
}

// ------------- Prep: out[c][r] = f16(src[r][c]) (+ lo residual) --------------
// Used only for W (1 block-layer).
template <bool WITH_LO>
__global__ __launch_bounds__(256) void transpose_f16_kernel(
    const float* __restrict__ src, _Float16* __restrict__ dstH,
    _Float16* __restrict__ dstL)
{
    __shared__ float tile[64 * 68];
    const size_t base = (size_t)blockIdx.z * BATCH_ELEMS;
    const int r0 = blockIdx.y * 64, c0 = blockIdx.x * 64;
    const int t = threadIdx.x;
    {
        int r = t >> 2, cq = (t & 3) * 16;
        const float* sp = src + base + (size_t)(r0 + r) * 512 + c0 + cq;
        *(float4*)&tile[r * 68 + cq]      = ((const float4*)sp)[0];
        *(float4*)&tile[r * 68 + cq + 4]  = ((const float4*)sp)[1];
        *(float4*)&tile[r * 68 + cq + 8]  = ((const float4*)sp)[2];
        *(float4*)&tile[r * 68 + cq + 12] = ((const float4*)sp)[3];
    }
    __syncthreads();
    {
        int c = t >> 2, rq = (t & 3) * 16;
        _Float16 hv[16], lv[16];
#pragma unroll
        for (int j = 0; j < 16; ++j) {
            float v = tile[(rq + j) * 68 + c];
            hv[j] = (_Float16)v;
            if (WITH_LO) lv[j] = (_Float16)(v - (float)hv[j]);
        }
        _Float16* dp = dstH + base + (size_t)(c0 + c) * 512 + r0 + rq;
        *(h8*)dp = *(h8*)&hv[0];
        *(h8*)(dp + 8) = *(h8*)&hv[8];
        if (WITH_LO) {
            _Float16* dl = dstL + base + (size_t)(c0 + c) * 512 + r0 + rq;
            *(h8*)dl = *(h8*)&lv[0];
            *(h8*)(dl + 8) = *(h8*)&lv[8];
        }
    }
}

// ------------- Prep: HT and PT in ONE launch (z<64: H, z>=64: P) -------------
__global__ __launch_bounds__(256) void transpose_hp_kernel(
    const float* __restrict__ H, const float* __restrict__ P,
    _Float16* __restrict__ HT, _Float16* __restrict__ PT)
{
    __shared__ float tile[64 * 68];
    const int z = blockIdx.z;
    const float* src = (z < NB) ? H : P;
    _Float16* dst = (z < NB) ? HT : PT;
    const size_t base = (size_t)(z < NB ? z : z - NB) * BATCH_ELEMS;
    const int r0 = blockIdx.y * 64, c0 = blockIdx.x * 64;
    const int t = threadIdx.x;
    {
        int r = t >> 2, cq = (t & 3) * 16;
        const float* sp = src + base + (size_t)(r0 + r) * 512 + c0 + cq;
        *(float4*)&tile[r * 68 + cq]      = ((const float4*)sp)[0];
        *(float4*)&tile[r * 68 + cq + 4]  = ((const float4*)sp)[1];
        *(float4*)&tile[r * 68 + cq + 8]  = ((const float4*)sp)[2];
        *(float4*)&tile[r * 68 + cq + 12] = ((const float4*)sp)[3];
    }
    __syncthreads();
    {
        int c = t >> 2, rq = (t & 3) * 16;
        _Float16 hv[16];
#pragma unroll
        for (int j = 0; j < 16; ++j) hv[j] = (_Float16)tile[(rq + j) * 68 + c];
        _Float16* dp = dst + base + (size_t)(c0 + c) * 512 + r0 + rq;
        *(h8*)dp = *(h8*)&hv[0];
        *(h8*)(dp + 8) = *(h8*)&hv[8];
    }
}

// ---------------- Kernel 1: F = tanh(X @ W), 2-term split f16 MFMA -----------
// Pipelined: 1 barrier / k-step, loads for k+1 issued before MFMA of k.
__global__ __launch_bounds__(256) void proj_tanh_kernel(
    const float* __restrict__ P, const float* __restrict__ H,
    const _Float16* __restrict__ WTH, const _Float16* __restrict__ WTL,
    _Float16* __restrict__ Fout)
{
    __shared__ __align__(16) _Float16 AsH[2][128 * 32];
    __shared__ __align__(16) _Float16 BsH[2][128 * 32], BsL[2][128 * 32];

    const int z = blockIdx.z;
    const float* X = z ? H : P;
    _Float16* F = Fout + (size_t)z * TOT_ELEMS;
    const int r0 = blockIdx.x * 128;
    const int n0 = blockIdx.y * 128;

    const int t = threadIdx.x;
    const int lane = t & 63, w = t >> 6;
    const int q = lane >> 4, c = lane & 15;
    const int wm = w >> 1, wn = w & 1;

    f4 acc[4][4] = {};

    const int ar = t >> 1, akq = (t & 1) << 4;   // A stage: row, k-offset 0/16
    const int br = t >> 1, bcp = (t & 1) << 1;   // B stage: n-row, chunk pair

    const float* apg = X + (size_t)(r0 + ar) * 512 + akq;
    const _Float16* bhg = WTH + (size_t)(n0 + br) * 512 + bcp * 8;
    const _Float16* blg = WTL + (size_t)(n0 + br) * 512 + bcp * 8;

    float av[16];
    h8 bh0, bh1, bl0, bl1;

    auto LOAD = [&](int k0) {
        *(float4*)&av[0]  = ((const float4*)(apg + k0))[0];
        *(float4*)&av[4]  = ((const float4*)(apg + k0))[1];
        *(float4*)&av[8]  = ((const float4*)(apg + k0))[2];
        *(float4*)&av[12] = ((const float4*)(apg + k0))[3];
        bh0 = ((const h8*)(bhg + k0))[0];
        bh1 = ((const h8*)(bhg + k0))[1];
        bl0 = ((const h8*)(blg + k0))[0];
        bl1 = ((const h8*)(blg + k0))[1];
    };
    auto STAGE = [&](int pp) {
        _Float16* asd = &AsH[pp][0];
        _Float16* bhd = &BsH[pp][0];
        _Float16* bld = &BsL[pp][0];
        const int cbase = akq >> 3;
#pragma unroll
        for (int jj = 0; jj < 2; ++jj) {
            h8 hv;
#pragma unroll
            for (int i = 0; i < 8; ++i) hv[i] = (_Float16)av[jj * 8 + i];
            *(h8*)&asd[swz(ar, cbase + jj)] = hv;
        }
        *(h8*)&bhd[swz(br, bcp)]     = bh0;
        *(h8*)&bhd[swz(br, bcp + 1)] = bh1;
        *(h8*)&bld[swz(br, bcp)]     = bl0;
        *(h8*)&bld[swz(br, bcp + 1)] = bl1;
    };

    LOAD(0);
    STAGE(0);

    int pp = 0;
    for (int k0 = 0; k0 < 512; k0 += 32) {
        __syncthreads();
        const bool more = (k0 + 32) < 512;
        if (more) LOAD(k0 + 32);

        const _Float16* ash = &AsH[pp][0];
        const _Float16* bhs = &BsH[pp][0];
        const _Float16* bls = &BsL[pp][0];
        h8 aH[4], bH[4], bL[4];
#pragma unroll
        for (int mi = 0; mi < 4; ++mi)
            aH[mi] = *(const h8*)&ash[swz(wm * 64 + mi * 16 + c, q)];
#pragma unroll
        for (int ni = 0; ni < 4; ++ni) {
            bH[ni] = *(const h8*)&bhs[swz(wn * 64 + ni * 16 + c, q)];
            bL[ni] = *(const h8*)&bls[swz(wn * 64 + ni * 16 + c, q)];
        }
#pragma unroll
        for (int mi = 0; mi < 4; ++mi)
#pragma unroll
            for (int ni = 0; ni < 4; ++ni) {
                acc[mi][ni] = __builtin_amdgcn_mfma_f32_16x16x32_f16(aH[mi], bH[ni], acc[mi][ni], 0, 0, 0);
                acc[mi][ni] = __builtin_amdgcn_mfma_f32_16x16x32_f16(aH[mi], bL[ni], acc[mi][ni], 0, 0, 0);
            }
        if (more) STAGE(pp ^ 1);
        pp ^= 1;
    }

#pragma unroll
    for (int mi = 0; mi < 4; ++mi)
#pragma unroll
        for (int ni = 0; ni < 4; ++ni) {
            int col = n0 + wn * 64 + ni * 16 + c;
            int rowb = r0 + wm * 64 + mi * 16 + q * 4;
#pragma unroll
            for (int r = 0; r < 4; ++r)
                F[(size_t)(rowb + r) * 512 + col] = (_Float16)fast_tanh(acc[mi][ni][r]);
        }
}

// ---------------- Kernel 2: S = F_p @ F_h^T, row softmax -> attn f16 ---------
__global__ __launch_bounds__(256) void score_softmax_kernel(
    const _Float16* __restrict__ Fbase, _Float16* __restrict__ attn)
{
    __shared__ __align__(16) _Float16 As[2][64 * 32];
    __shared__ __align__(16) _Float16 Bs[2][512 * 32];
    __shared__ float redM[4 * 64], redS[4 * 64];

    const _Float16* Fp = Fbase;
    const _Float16* Fh = Fbase + TOT_ELEMS;
    const int b = blockIdx.y;
    const int p0 = blockIdx.x * 64;
    const size_t fb = (size_t)b * BATCH_ELEMS;

    const int t = threadIdx.x, lane = t & 63, w = t >> 6;
    const int q = lane >> 4, c = lane & 15;

    f4 acc[4][8] = {};

    const int arow = t >> 2, ach = t & 3;
    const _Float16* apg = Fp + fb + (size_t)(p0 + arow) * 512 + ach * 8;
    const _Float16* bpg = Fh + fb + (size_t)(t * 2) * 512;

    h8 areg, breg[2][4];

    auto LOAD = [&](int k0) {
        areg = *(const h8*)(apg + k0);
#pragma unroll
        for (int rr = 0; rr < 2; ++rr)
#pragma unroll
            for (int ch = 0; ch < 4; ++ch)
                breg[rr][ch] = *(const h8*)(bpg + (size_t)rr * 512 + k0 + ch * 8);
    };
    auto STAGE = [&](int pp) {
        *(h8*)&As[pp][swz(arow, ach)] = areg;
#pragma unroll
        for (int rr = 0; rr < 2; ++rr)
#pragma unroll
            for (int ch = 0; ch < 4; ++ch)
                *(h8*)&Bs[pp][swz(t * 2 + rr, ch)] = breg[rr][ch];
    };

    LOAD(0);
    STAGE(0);

    int pp = 0;
    for (int k0 = 0; k0 < 512; k0 += 32) {
        __syncthreads();
        const bool more = (k0 + 32) < 512;
        if (more) LOAD(k0 + 32);

        h8 a[4], bb[8];
#pragma unroll
        for (int mt = 0; mt < 4; ++mt) a[mt] = *(const h8*)&As[pp][swz(mt * 16 + c, q)];
#pragma unroll
        for (int nt = 0; nt < 8; ++nt) bb[nt] = *(const h8*)&Bs[pp][swz(w * 128 + nt * 16 + c, q)];
#pragma unroll
        for (int mt = 0; mt < 4; ++mt)
#pragma unroll
            for (int nt = 0; nt < 8; ++nt)
                acc[mt][nt] = __builtin_amdgcn_mfma_f32_16x16x32_f16(a[mt], bb[nt], acc[mt][nt], 0, 0, 0);
        if (more) STAGE(pp ^ 1);
        pp ^= 1;
    }

    // ---- softmax over the 512 cols; rows owned: mt*16 + q*4 + r ----
    float rmax[4][4];
#pragma unroll
    for (int mt = 0; mt < 4; ++mt)
#pragma unroll
        for (int r = 0; r < 4; ++r) {
            float m = acc[mt][0][r];
#pragma unroll
            for (int nt = 1; nt < 8; ++nt) m = fmaxf(m, acc[mt][nt][r]);
            rmax[mt][r] = m;
        }
#pragma unroll
    for (int s = 1; s < 16; s <<= 1)
#pragma unroll
        for (int mt = 0; mt < 4; ++mt)
#pragma unroll
            for (int r = 0; r < 4; ++r)
                rmax[mt][r] = fmaxf(rmax[mt][r], __shfl_xor(rmax[mt][r], s, 64));
    if (c == 0)
#pragma unroll
        for (int mt = 0; mt < 4; ++mt)
#pragma unroll
            for (int r = 0; r < 4; ++r)
                redM[w * 64 + mt * 16 + q * 4 + r] = rmax[mt][r];
    __syncthreads();

    float gmax[4][4];
#pragma unroll
    for (int mt = 0; mt < 4; ++mt)
#pragma unroll
        for (int r = 0; r < 4; ++r) {
            int row = mt * 16 + q * 4 + r;
            float m = redM[row];
#pragma unroll
            for (int w4 = 1; w4 < 4; ++w4) m = fmaxf(m, redM[w4 * 64 + row]);
            gmax[mt][r] = m;
        }

    float rsum[4][4] = {};
#pragma unroll
    for (int mt = 0; mt < 4; ++mt)
#pragma unroll
        for (int nt = 0; nt < 8; ++nt)
#pragma unroll
            for (int r = 0; r < 4; ++r) {
                float e = __expf(acc[mt][nt][r] - gmax[mt][r]);
                acc[mt][nt][r] = e;
                rsum[mt][r] += e;
            }
#pragma unroll
    for (int s = 1; s < 16; s <<= 1)
#pragma unroll
        for (int mt = 0; mt < 4; ++mt)
#pragma unroll
            for (int r = 0; r < 4; ++r)
                rsum[mt][r] += __shfl_xor(rsum[mt][r], s, 64);
    if (c == 0)
#pragma unroll
        for (int mt = 0; mt < 4; ++mt)
#pragma unroll
            for (int r = 0; r < 4; ++r)
                redS[w * 64 + mt * 16 + q * 4 + r] = rsum[mt][r];
    __syncthreads();

    float inv[4][4];
#pragma unroll
    for (int mt = 0; mt < 4; ++mt)
#pragma unroll
        for (int r = 0; r < 4; ++r) {
            int row = mt * 16 + q * 4 + r;
            float s = redS[row] + redS[64 + row] + redS[128 + row] + redS[192 + row];
            inv[mt][r] = 1.0f / s;
        }

#pragma unroll
    for (int mt = 0; mt < 4; ++mt)
#pragma unroll
        for (int nt = 0; nt < 8; ++nt) {
            int col = w * 128 + nt * 16 + c;
#pragma unroll
            for (int r = 0; r < 4; ++r) {
                int row = p0 + mt * 16 + q * 4 + r;
                attn[fb + (size_t)row * 512 + col] = (_Float16)(acc[mt][nt][r] * inv[mt][r]);
            }
        }
}

// ------- Kernels 3+4 merged: C = A(^T) @ B; z<64: betas (attn@H via HT),
//         z>=64: alphas (attn^T@P via PT). Pipelined like proj. --------------
__global__ __launch_bounds__(256) void out_gemm_kernel(
    const _Float16* __restrict__ Amat, const _Float16* __restrict__ HT,
    const _Float16* __restrict__ PT, float* __restrict__ out)
{
    __shared__ __align__(16) _Float16 As[2][128 * 32];
    __shared__ __align__(16) _Float16 Bs[2][128 * 32];

    const int zz = blockIdx.z;
    const bool transA = zz >= NB;
    const int b = transA ? zz - NB : zz;
    const _Float16* BT = transA ? PT : HT;
    float* Cout = transA ? out + TOT_ELEMS : out;

    const int bn = blockIdx.x * 128, bm = blockIdx.y * 128;
    const size_t base = (size_t)b * BATCH_ELEMS;

    const int t = threadIdx.x, lane = t & 63, w = t >> 6;
    const int q = lane >> 4, c = lane & 15;
    const int wm = w >> 1, wn = w & 1;

    f4 acc[4][4] = {};

    // A-stage addressing (both variants), B-stage addressing
    const int row2 = t >> 1, cp2 = (t & 1) * 2;                 // direct paths
    const int kk = t >> 3, m0 = (t & 7) * 16;                   // transA path
    const _Float16* apg_d = Amat + base + (size_t)(bm + row2) * 512 + cp2 * 8;
    const _Float16* apg_t = Amat + base + (size_t)kk * 512 + bm + m0;
    const _Float16* bpg   = BT + base + (size_t)(bn + row2) * 512 + cp2 * 8;

    h8 a0, a1, b0, b1;

    auto LOAD = [&](int k0) {
        if (!transA) {
            a0 = ((const h8*)(apg_d + k0))[0];
            a1 = ((const h8*)(apg_d + k0))[1];
        } else {
            a0 = ((const h8*)(apg_t + (size_t)k0 * 512))[0];
            a1 = ((const h8*)(apg_t + (size_t)k0 * 512))[1];
        }
        b0 = ((const h8*)(bpg + k0))[0];
        b1 = ((const h8*)(bpg + k0))[1];
    };
    auto STAGE = [&](int pp) {
        if (!transA) {
            *(h8*)&As[pp][swz(row2, cp2)]     = a0;
            *(h8*)&As[pp][swz(row2, cp2 + 1)] = a1;
        } else {
#pragma unroll
            for (int j = 0; j < 8; ++j) {
                As[pp][swz(m0 + j, kk >> 3) + (kk & 7)]     = a0[j];
                As[pp][swz(m0 + 8 + j, kk >> 3) + (kk & 7)] = a1[j];
            }
        }
        *(h8*)&Bs[pp][swz(row2, cp2)]     = b0;
        *(h8*)&Bs[pp][swz(row2, cp2 + 1)] = b1;
    };

    LOAD(0);
    STAGE(0);

    int pp = 0;
    for (int k0 = 0; k0 < 512; k0 += 32) {
        __syncthreads();
        const bool more = (k0 + 32) < 512;
        if (more) LOAD(k0 + 32);

        h8 a[4], bb[4];
#pragma unroll
        for (int mi = 0; mi < 4; ++mi) a[mi] = *(const h8*)&As[pp][swz(wm * 64 + mi * 16 + c, q)];
#pragma unroll
        for (int ni = 0; ni < 4; ++ni) bb[ni] = *(const h8*)&Bs[pp][swz(wn * 64 + ni * 16 + c, q)];
#pragma unroll
        for (int mi = 0; mi < 4; ++mi)
#pragma unroll
            for (int ni = 0; ni < 4; ++ni)
                acc[mi][ni] = __builtin_amdgcn_mfma_f32_16x16x32_f16(a[mi], bb[ni], acc[mi][ni], 0, 0, 0);
        if (more) STAGE(pp ^ 1);
        pp ^= 1;
    }

#pragma unroll
    for (int mi = 0; mi < 4; ++mi)
#pragma unroll
        for (int ni = 0; ni < 4; ++ni) {
            int col = bn + wn * 64 + ni * 16 + c;
            int rowb = bm + wm * 64 + mi * 16 + q * 4;
#pragma unroll
            for (int r = 0; r < 4; ++r)
                Cout[base + (size_t)(rowb + r) * 512 + col] = acc[mi][ni][r];
        }
}

extern "C" void kernel_launch(void* const* d_in, const int* in_sizes, int n_in,
                              void* d_out, int out_size, void* d_ws, size_t ws_size,
                              hipStream_t stream) {
    const float* P = (const float*)d_in[0];
    const float* H = (const float*)d_in[1];
    const float* W = (const float*)d_in[2];
    float* out = (float*)d_out;

    _Float16* ws16 = (_Float16*)d_ws;
    _Float16* F    = ws16;                       // F_p|F_h: 2*16777216 (dead after score)
    _Float16* PT   = ws16;                       // reuses F region after score
    _Float16* HT   = ws16 + TOT_ELEMS;
    _Float16* attn = ws16 + 2 * TOT_ELEMS;       // 16777216
    _Float16* WTH  = attn;                       // WT lives in attn region (dead
    _Float16* WTL  = attn + BATCH_ELEMS;         //  before score writes attn)

    transpose_f16_kernel<true><<<dim3(8, 8, 1), 256, 0, stream>>>(W, WTH, WTL);
    proj_tanh_kernel<<<dim3(256, 4, 2), 256, 0, stream>>>(P, H, WTH, WTL, F);
    score_softmax_kernel<<<dim3(8, NB), 256, 0, stream>>>(F, attn);
    transpose_hp_kernel<<<dim3(8, 8, 2 * NB), 256, 0, stream>>>(H, P, HT, PT);
    out_gemm_kernel<<<dim3(4, 4, 2 * NB), 256, 0, stream>>>(attn, HT, PT, out);
}